// Round 1
// baseline (509.909 us; speedup 1.0000x reference)
//
#include <hip/hip_runtime.h>
#include <hip/hip_bf16.h>

#define TSEQ 256
#define NBATCH 2
#define NAG 8      // agent dim (N)
#define NH 8       // heads
#define HD 64      // head dim
#define EE 512     // embed
#define WHALF 16
#define WW 33      // window size
#define WN 264     // WW*NAG

// ---------------- projection GEMM (fp32, tiled 64x64x16) -----------------
// out[i,f] = (sum_e x[i,e]*W[f,e] + b[f]) * scale     (x: 4096x512, W: 512x512 row-major)
__global__ __launch_bounds__(256)
void proj_kernel(const float* __restrict__ x, const float* __restrict__ Wt,
                 const float* __restrict__ bias, float* __restrict__ out,
                 float scale)
{
    __shared__ float As[16][68];   // [kk][row], padded
    __shared__ float Bs[16][68];
    const int tid = threadIdx.x;
    const int i0 = blockIdx.x * 64;
    const int f0 = blockIdx.y * 64;
    const int r = tid >> 4;        // 0..15
    const int c = tid & 15;        // 0..15
    const int lrow = tid >> 2;     // 0..63
    const int lk4  = (tid & 3) * 4;

    float acc[4][4] = {};

    for (int k0 = 0; k0 < EE; k0 += 16) {
        float4 a4 = *reinterpret_cast<const float4*>(&x [(i0 + lrow) * EE + k0 + lk4]);
        float4 b4 = *reinterpret_cast<const float4*>(&Wt[(f0 + lrow) * EE + k0 + lk4]);
        As[lk4 + 0][lrow] = a4.x; As[lk4 + 1][lrow] = a4.y;
        As[lk4 + 2][lrow] = a4.z; As[lk4 + 3][lrow] = a4.w;
        Bs[lk4 + 0][lrow] = b4.x; Bs[lk4 + 1][lrow] = b4.y;
        Bs[lk4 + 2][lrow] = b4.z; Bs[lk4 + 3][lrow] = b4.w;
        __syncthreads();
        #pragma unroll
        for (int kk = 0; kk < 16; ++kk) {
            float4 av = *reinterpret_cast<const float4*>(&As[kk][r * 4]);
            float4 bv = *reinterpret_cast<const float4*>(&Bs[kk][c * 4]);
            float a[4] = {av.x, av.y, av.z, av.w};
            float b[4] = {bv.x, bv.y, bv.z, bv.w};
            #pragma unroll
            for (int xx = 0; xx < 4; ++xx)
                #pragma unroll
                for (int yy = 0; yy < 4; ++yy)
                    acc[xx][yy] += a[xx] * b[yy];
        }
        __syncthreads();
    }
    #pragma unroll
    for (int xx = 0; xx < 4; ++xx) {
        const int i = i0 + r * 4 + xx;
        #pragma unroll
        for (int yy = 0; yy < 4; ++yy) {
            const int f = f0 + c * 4 + yy;
            out[i * EE + f] = (acc[xx][yy] + bias[f]) * scale;
        }
    }
}

// ---------------- windowed attention -----------------
// One block per (b, t, n-half): computes logits, softmax, attn output, PV.
__global__ __launch_bounds__(256)
void attn_kernel(const float* __restrict__ q,   // [B,T,N,E] pre-scaled
                 const float* __restrict__ k,   // [B,T,N,E]
                 const float* __restrict__ v,   // [B,T,N,E]
                 const unsigned char* __restrict__ kpm,  // [B,T,N] bool
                 float* __restrict__ out,       // [B,T,N,E]
                 float* __restrict__ attn)      // [B,T,N,WN,NH]
{
    __shared__ float q_s[4 * EE];          // 4 query agents x 512
    __shared__ float kv_s[NAG * EE];       // one j-step of k or v (all 8 agents)
    __shared__ float log_s[32 * WN];       // 32 rows (n_local*8+h) x 264

    const int bid = blockIdx.x;
    const int half = bid & 1;              // which n-half
    const int bt = bid >> 1;               // b*T + t
    const int b = bt >> 8;
    const int t = bt & 255;
    const int tid = threadIdx.x;
    const int n0 = half * 4;

    // load q for 4 agents (contiguous 2048 floats)
    {
        const float* qp = q + (size_t)bt * (NAG * EE) + half * (4 * EE);
        #pragma unroll
        for (int i = tid * 4; i < 4 * EE; i += 256 * 4)
            *reinterpret_cast<float4*>(&q_s[i]) = *reinterpret_cast<const float4*>(&qp[i]);
    }
    // init logits to -inf
    for (int i = tid; i < 32 * WN; i += 256) log_s[i] = -INFINITY;
    __syncthreads();

    // ---- logits: one dot per thread per window step ----
    const int m  = tid & 7;
    const int hh = (tid >> 3) & 7;
    const int nl = tid >> 6;               // 0..3
    for (int wi = 0; wi < WW; ++wi) {
        const int j = t + wi - WHALF;
        if (j < 0 || j >= TSEQ) continue;
        __syncthreads();                    // kv_s free from previous iter
        {
            const float* kp = k + (size_t)(b * TSEQ + j) * (NAG * EE);
            #pragma unroll
            for (int i = tid * 4; i < NAG * EE; i += 256 * 4)
                *reinterpret_cast<float4*>(&kv_s[i]) = *reinterpret_cast<const float4*>(&kp[i]);
        }
        __syncthreads();
        const bool masked = kpm[(b * TSEQ + j) * NAG + m] != 0;
        const float* qq = &q_s[nl * EE + hh * HD];
        const float* kk = &kv_s[m * EE + hh * HD];
        float s = 0.f;
        #pragma unroll
        for (int d4 = 0; d4 < HD / 4; ++d4) {
            float4 qa = *reinterpret_cast<const float4*>(&qq[d4 * 4]);
            float4 ka = *reinterpret_cast<const float4*>(&kk[d4 * 4]);
            s += qa.x * ka.x + qa.y * ka.y + qa.z * ka.z + qa.w * ka.w;
        }
        log_s[(nl * 8 + hh) * WN + wi * NAG + m] = masked ? -INFINITY : s;
    }
    __syncthreads();

    // ---- softmax: 8 threads per row, 32 rows ----
    {
        const int row = tid >> 3;
        const int sub = tid & 7;
        float* Lr = &log_s[row * WN];
        float mx = -INFINITY;
        for (int i = sub; i < WN; i += 8) mx = fmaxf(mx, Lr[i]);
        mx = fmaxf(mx, __shfl_xor(mx, 1));
        mx = fmaxf(mx, __shfl_xor(mx, 2));
        mx = fmaxf(mx, __shfl_xor(mx, 4));
        float sume = 0.f;
        for (int i = sub; i < WN; i += 8) {
            const float xv = Lr[i];
            const float p = (xv == -INFINITY) ? 0.f : __expf(xv - mx);
            Lr[i] = p;
            sume += p;
        }
        sume += __shfl_xor(sume, 1);
        sume += __shfl_xor(sume, 2);
        sume += __shfl_xor(sume, 4);
        const float inv = 1.f / sume;
        for (int i = sub; i < WN; i += 8) Lr[i] *= inv;
    }
    __syncthreads();

    // ---- write attn (coalesced): per-block region = 4 agents x 2112 floats ----
    {
        float* ap = attn + (size_t)bt * (NAG * WN * NH) + (size_t)n0 * (WN * NH);
        for (int L = tid; L < 4 * WN * NH; L += 256) {
            const int h2   = L & 7;
            const int rem  = L >> 3;          // n_local*264 + wim
            const int n2   = rem / WN;
            const int wim  = rem - n2 * WN;
            ap[L] = log_s[(n2 * 8 + h2) * WN + wim];
        }
    }

    // ---- PV: each thread owns 2 float4 output chunks ----
    float4 acc[2];
    acc[0] = make_float4(0.f, 0.f, 0.f, 0.f);
    acc[1] = make_float4(0.f, 0.f, 0.f, 0.f);
    for (int wi = 0; wi < WW; ++wi) {
        const int j = t + wi - WHALF;
        if (j < 0 || j >= TSEQ) continue;
        __syncthreads();                    // kv_s free
        {
            const float* vp = v + (size_t)(b * TSEQ + j) * (NAG * EE);
            #pragma unroll
            for (int i = tid * 4; i < NAG * EE; i += 256 * 4)
                *reinterpret_cast<float4*>(&kv_s[i]) = *reinterpret_cast<const float4*>(&vp[i]);
        }
        __syncthreads();
        #pragma unroll
        for (int g = 0; g < 2; ++g) {
            const int o0 = (tid + 256 * g) * 4;   // 0..2044
            const int dd = o0 & 63;
            const int h2 = (o0 >> 6) & 7;
            const int n2 = o0 >> 9;
            const float* Ar = &log_s[(n2 * 8 + h2) * WN + wi * NAG];
            const float* Vr = &kv_s[h2 * HD + dd];
            float4 a = acc[g];
            #pragma unroll
            for (int mm = 0; mm < NAG; ++mm) {
                const float w = Ar[mm];
                float4 vv = *reinterpret_cast<const float4*>(&Vr[mm * EE]);
                a.x += w * vv.x; a.y += w * vv.y; a.z += w * vv.z; a.w += w * vv.w;
            }
            acc[g] = a;
        }
    }
    {
        float* op = out + (size_t)bt * (NAG * EE) + half * (4 * EE);
        *reinterpret_cast<float4*>(&op[tid * 4])             = acc[0];
        *reinterpret_cast<float4*>(&op[(tid + 256) * 4])     = acc[1];
    }
}

extern "C" void kernel_launch(void* const* d_in, const int* in_sizes, int n_in,
                              void* d_out, int out_size, void* d_ws, size_t ws_size,
                              hipStream_t stream) {
    const float* query = (const float*)d_in[0];
    const float* key   = (const float*)d_in[1];
    const float* value = (const float*)d_in[2];
    const unsigned char* kpm = (const unsigned char*)d_in[3];
    const float* Wq = (const float*)d_in[4];
    const float* bq = (const float*)d_in[5];
    const float* Wk = (const float*)d_in[6];
    const float* bk = (const float*)d_in[7];
    const float* Wv = (const float*)d_in[8];
    const float* bv = (const float*)d_in[9];

    float* out  = (float*)d_out;                       // [B,T,N,E] = 2,097,152 floats
    float* attn = out + (size_t)NBATCH * TSEQ * NAG * EE;  // [B,T,N,WN,NH]

    float* qb = (float*)d_ws;                          // 3 x 4096x512 fp32 in workspace
    float* kb = qb + (size_t)4096 * EE;
    float* vb = kb + (size_t)4096 * EE;

    dim3 gp(64, 8, 1);
    proj_kernel<<<gp, 256, 0, stream>>>(query, Wq, bq, qb, 0.125f);  // 1/sqrt(64)
    proj_kernel<<<gp, 256, 0, stream>>>(key,   Wk, bk, kb, 1.0f);
    proj_kernel<<<gp, 256, 0, stream>>>(value, Wv, bv, vb, 1.0f);

    attn_kernel<<<NBATCH * TSEQ * 2, 256, 0, stream>>>(qb, kb, vb, kpm, out, attn);
}

// Round 2
// 153.715 us; speedup vs baseline: 3.3172x; 3.3172x over previous
//
#include <hip/hip_runtime.h>
#include <hip/hip_bf16.h>

#define TSEQ 256
#define NBATCH 2
#define NAG 8
#define NH 8
#define HD 64
#define EE 512
#define WHALF 16
#define WW 33
#define WN 264   // WW*NAG

typedef __attribute__((ext_vector_type(8))) short short8;
typedef __attribute__((ext_vector_type(4))) float f32x4;

// ---- dynamic LDS layout (bytes) ----
#define KS_OFF   0          // 384 rows x 128B (XOR-swizzled)      = 49152
#define VT_OFF   49152      // 64 rows x 768B  (XOR-swizzled)      = 49152
#define P_OFF    98304      // 32 rows x 1552B fp32 (+bf16 alias)  = 49664
#define QS_OFF   147968     // 32 rows x 128B  (XOR-swizzled)      = 4096
#define KM_OFF   152064     // 384B key-valid mask (+pad)
#define SMEM_BYTES 152576

static __device__ __forceinline__ unsigned short f2bf(float f) {
    unsigned int u = __float_as_uint(f);
    unsigned int r = (u + 0x7FFFu + ((u >> 16) & 1u)) >> 16;
    return (unsigned short)r;
}

// ---------------- projection GEMM (fp32 math, bf16 out) -----------------
__global__ __launch_bounds__(256)
void proj_kernel(const float* __restrict__ x, const float* __restrict__ Wt,
                 const float* __restrict__ bias, unsigned short* __restrict__ out,
                 float scale)
{
    __shared__ float As[16][68];
    __shared__ float Bs[16][68];
    const int tid = threadIdx.x;
    const int i0 = blockIdx.x * 64;
    const int f0 = blockIdx.y * 64;
    const int r = tid >> 4;
    const int c = tid & 15;
    const int lrow = tid >> 2;
    const int lk4  = (tid & 3) * 4;

    float acc[4][4] = {};

    for (int k0 = 0; k0 < EE; k0 += 16) {
        float4 a4 = *reinterpret_cast<const float4*>(&x [(i0 + lrow) * EE + k0 + lk4]);
        float4 b4 = *reinterpret_cast<const float4*>(&Wt[(f0 + lrow) * EE + k0 + lk4]);
        As[lk4 + 0][lrow] = a4.x; As[lk4 + 1][lrow] = a4.y;
        As[lk4 + 2][lrow] = a4.z; As[lk4 + 3][lrow] = a4.w;
        Bs[lk4 + 0][lrow] = b4.x; Bs[lk4 + 1][lrow] = b4.y;
        Bs[lk4 + 2][lrow] = b4.z; Bs[lk4 + 3][lrow] = b4.w;
        __syncthreads();
        #pragma unroll
        for (int kk = 0; kk < 16; ++kk) {
            float4 av = *reinterpret_cast<const float4*>(&As[kk][r * 4]);
            float4 bv = *reinterpret_cast<const float4*>(&Bs[kk][c * 4]);
            float a[4] = {av.x, av.y, av.z, av.w};
            float b[4] = {bv.x, bv.y, bv.z, bv.w};
            #pragma unroll
            for (int xx = 0; xx < 4; ++xx)
                #pragma unroll
                for (int yy = 0; yy < 4; ++yy)
                    acc[xx][yy] += a[xx] * b[yy];
        }
        __syncthreads();
    }
    float4 bb = *reinterpret_cast<const float4*>(&bias[f0 + c * 4]);
    const float bv4[4] = {bb.x, bb.y, bb.z, bb.w};
    #pragma unroll
    for (int xx = 0; xx < 4; ++xx) {
        const int i = i0 + r * 4 + xx;
        ushort4 s4;
        s4.x = f2bf((acc[xx][0] + bv4[0]) * scale);
        s4.y = f2bf((acc[xx][1] + bv4[1]) * scale);
        s4.z = f2bf((acc[xx][2] + bv4[2]) * scale);
        s4.w = f2bf((acc[xx][3] + bv4[3]) * scale);
        *reinterpret_cast<ushort4*>(&out[(size_t)i * EE + f0 + c * 4]) = s4;
    }
}

// ---------------- MFMA windowed attention -----------------
// grid: 256 blocks, bid = h*32 + (b*16 + tc); 512 threads.
__global__ __launch_bounds__(512, 1)
void attn_mfma_kernel(const unsigned short* __restrict__ qb,
                      const unsigned short* __restrict__ kb,
                      const unsigned short* __restrict__ vb,
                      const unsigned char* __restrict__ kpm,
                      float* __restrict__ out,
                      float* __restrict__ attn)
{
    extern __shared__ char smem[];
    const int bid = blockIdx.x;
    const int h   = bid >> 5;
    const int btc = bid & 31;
    const int b   = btc >> 4;
    const int tc  = btc & 15;
    const int t0  = tc * 16;
    const int j0  = t0 - WHALF;
    const int tid = threadIdx.x;
    const int lane = tid & 63;
    const int wid  = tid >> 6;

    // ---- stage K: 384 key-rows x 64 bf16, row stride 128B, XOR swizzle ----
    for (int tt = tid; tt < 3072; tt += 512) {
        const int row = tt >> 3, ch = tt & 7;
        const int jj = row >> 3, m = row & 7;
        const int j = j0 + jj;
        char* dst = smem + KS_OFF + row * 128 + ((ch * 16) ^ ((row & 7) << 4));
        if (j >= 0 && j < TSEQ) {
            *(short8*)dst = *(const short8*)(kb + (((size_t)(b * TSEQ + j) * NAG + m) * EE + h * HD + ch * 8));
        } else {
            short8 z = {0,0,0,0,0,0,0,0};
            *(short8*)dst = z;
        }
    }
    // ---- stage Vt (transposed): 64 d-rows x 384, row stride 768B, XOR swizzle ----
    for (int tt = tid; tt < 3072; tt += 512) {
        const int key = tt >> 3, dch = tt & 7;
        const int jj = key >> 3, m = key & 7;
        const int j = j0 + jj;
        unsigned short tv[8] = {0,0,0,0,0,0,0,0};
        if (j >= 0 && j < TSEQ) {
            short8 val = *(const short8*)(vb + (((size_t)(b * TSEQ + j) * NAG + m) * EE + h * HD + dch * 8));
            #pragma unroll
            for (int i = 0; i < 8; ++i) tv[i] = (unsigned short)val[i];
        }
        #pragma unroll
        for (int i = 0; i < 8; ++i) {
            const int d = dch * 8 + i;
            *(unsigned short*)(smem + VT_OFF + d * 768 + ((key * 2) ^ ((d & 7) << 4))) = tv[i];
        }
    }
    // ---- key-valid mask ----
    if (tid < 384) {
        const int jj = tid >> 3, m = tid & 7;
        const int j = j0 + jj;
        smem[KM_OFF + tid] = (j >= 0 && j < TSEQ && kpm[(b * TSEQ + j) * NAG + m] == 0) ? 1 : 0;
    }
    __syncthreads();

    for (int sub = 0; sub < 4; ++sub) {
        const int ts0 = t0 + sub * 4;    // 4 t-values, 32 query rows

        // ---- stage Qs: 32 rows x 64 bf16 ----
        if (tid < 256) {
            const int rr = tid >> 3, ch = tid & 7;
            const int t = ts0 + (rr >> 3), n = rr & 7;
            char* dst = smem + QS_OFF + rr * 128 + ((ch * 16) ^ ((rr & 7) << 4));
            *(short8*)dst = *(const short8*)(qb + (((size_t)(b * TSEQ + t) * NAG + n) * EE + h * HD + ch * 8));
        }
        __syncthreads();

        // ---- QK^T: D[32 x 384]; wave: rfrag = wid&1, colfrags cf = (wid>>1)+4*i ----
        {
            f32x4 acc[6];
            #pragma unroll
            for (int i = 0; i < 6; ++i) acc[i] = (f32x4){0.f, 0.f, 0.f, 0.f};
            const int arow = (wid & 1) * 16 + (lane & 15);
            #pragma unroll
            for (int ks = 0; ks < 2; ++ks) {
                short8 afr = *(short8*)(smem + QS_OFF + arow * 128 +
                                        ((ks * 64 + (lane >> 4) * 16) ^ ((arow & 7) << 4)));
                #pragma unroll
                for (int i = 0; i < 6; ++i) {
                    const int cf = (wid >> 1) + 4 * i;
                    const int krow = cf * 16 + (lane & 15);
                    short8 bfr = *(short8*)(smem + KS_OFF + krow * 128 +
                                            ((ks * 64 + (lane >> 4) * 16) ^ ((krow & 7) << 4)));
                    acc[i] = __builtin_amdgcn_mfma_f32_16x16x32_bf16(afr, bfr, acc[i], 0, 0, 0);
                }
            }
            #pragma unroll
            for (int i = 0; i < 6; ++i) {
                const int cf = (wid >> 1) + 4 * i;
                const int col = cf * 16 + (lane & 15);
                const int r0 = (wid & 1) * 16 + (lane >> 4) * 4;
                #pragma unroll
                for (int rg = 0; rg < 4; ++rg)
                    ((float*)(smem + P_OFF + (size_t)(r0 + rg) * 1552))[col] = acc[i][rg];
            }
        }
        __syncthreads();

        // ---- softmax + attn store + bf16 repack (row rr owned by 16 lanes of one wave) ----
        {
            const int rr = tid >> 4, s16 = tid & 15;
            const int dtile = sub * 4 + (rr >> 3);
            const int win0 = dtile * 8;
            const int t = t0 + dtile, n = rr & 7;
            float* prow = (float*)(smem + P_OFF + (size_t)rr * 1552);
            const unsigned char* km = (const unsigned char*)(smem + KM_OFF);

            float vals[17];
            float mx = -INFINITY;
            #pragma unroll
            for (int k2 = 0; k2 < 17; ++k2) {
                const int cc = s16 + 16 * k2;
                float xv = -INFINITY;
                if (cc < WN) {
                    const int c = win0 + cc;
                    if (km[c]) xv = prow[c];
                }
                vals[k2] = xv;
                mx = fmaxf(mx, xv);
            }
            mx = fmaxf(mx, __shfl_xor(mx, 1));
            mx = fmaxf(mx, __shfl_xor(mx, 2));
            mx = fmaxf(mx, __shfl_xor(mx, 4));
            mx = fmaxf(mx, __shfl_xor(mx, 8));
            float sum = 0.f;
            #pragma unroll
            for (int k2 = 0; k2 < 17; ++k2) {
                const float p = (vals[k2] == -INFINITY) ? 0.f : __expf(vals[k2] - mx);
                vals[k2] = p;
                sum += p;
            }
            sum += __shfl_xor(sum, 1);
            sum += __shfl_xor(sum, 2);
            sum += __shfl_xor(sum, 4);
            sum += __shfl_xor(sum, 8);
            const float inv = 1.f / sum;
            #pragma unroll
            for (int k2 = 0; k2 < 17; ++k2) {
                const int cc = s16 + 16 * k2;
                if (cc < WN) prow[win0 + cc] = vals[k2] * inv;
            }

            // conversion + global attn write: read fp32 (all window cols), stash, then bf16 write
            const int c0 = s16;
            float pr[24];
            float* ap = attn + ((((size_t)(b * TSEQ + t) * NAG + n) * WN) * NH + h);
            #pragma unroll
            for (int k2 = 0; k2 < 24; ++k2) {
                const int c = c0 + 16 * k2;
                const bool in = (c >= win0) && (c < win0 + WN);
                float p = 0.f;
                if (in) p = prow[c];
                pr[k2] = p;
                if (in) ap[(size_t)(c - win0) * NH] = p;
            }
            // ensure all LDS reads above have completed before aliasing bf16 writes
            __builtin_amdgcn_sched_barrier(0);
            asm volatile("s_waitcnt lgkmcnt(0)" ::: "memory");
            __builtin_amdgcn_sched_barrier(0);
            #pragma unroll
            for (int k2 = 0; k2 < 24; ++k2) {
                const int c = c0 + 16 * k2;
                const int ib = (2 * c) ^ ((rr & 7) << 4);
                *(unsigned short*)(smem + P_OFF + (size_t)rr * 1552 + ib) = f2bf(pr[k2]);
            }
        }
        __syncthreads();

        // ---- PV: D[32 x 64]; wave: rfrag = wid&1, dfrag = wid>>1 ----
        {
            f32x4 acc = (f32x4){0.f, 0.f, 0.f, 0.f};
            const int rfrag = wid & 1, dfrag = wid >> 1;
            const int arow = rfrag * 16 + (lane & 15);
            const int drow = dfrag * 16 + (lane & 15);
            #pragma unroll
            for (int ms = 0; ms < 12; ++ms) {
                short8 afr = *(short8*)(smem + P_OFF + (size_t)arow * 1552 +
                                        ((ms * 64 + (lane >> 4) * 16) ^ ((arow & 7) << 4)));
                short8 bfr = *(short8*)(smem + VT_OFF + drow * 768 +
                                        ((ms * 64 + (lane >> 4) * 16) ^ ((drow & 7) << 4)));
                acc = __builtin_amdgcn_mfma_f32_16x16x32_bf16(afr, bfr, acc, 0, 0, 0);
            }
            const int r0 = rfrag * 16 + (lane >> 4) * 4;
            const int d = dfrag * 16 + (lane & 15);
            #pragma unroll
            for (int rg = 0; rg < 4; ++rg) {
                const int rr = r0 + rg;
                const int t = ts0 + (rr >> 3), n = rr & 7;
                out[((size_t)(b * TSEQ + t) * NAG + n) * EE + h * HD + d] = acc[rg];
            }
        }
        __syncthreads();   // protect P32/Qs overwrite next sub
    }
}

extern "C" void kernel_launch(void* const* d_in, const int* in_sizes, int n_in,
                              void* d_out, int out_size, void* d_ws, size_t ws_size,
                              hipStream_t stream) {
    const float* query = (const float*)d_in[0];
    const float* key   = (const float*)d_in[1];
    const float* value = (const float*)d_in[2];
    const unsigned char* kpm = (const unsigned char*)d_in[3];
    const float* Wq = (const float*)d_in[4];
    const float* bq = (const float*)d_in[5];
    const float* Wk = (const float*)d_in[6];
    const float* bk = (const float*)d_in[7];
    const float* Wv = (const float*)d_in[8];
    const float* bv = (const float*)d_in[9];

    float* out  = (float*)d_out;
    float* attn = out + (size_t)NBATCH * TSEQ * NAG * EE;

    unsigned short* qbf = (unsigned short*)d_ws;               // 3 x 4 MB bf16
    unsigned short* kbf = qbf + (size_t)4096 * EE;
    unsigned short* vbf = kbf + (size_t)4096 * EE;

    dim3 gp(64, 8, 1);
    proj_kernel<<<gp, 256, 0, stream>>>(query, Wq, bq, qbf, 0.125f);
    proj_kernel<<<gp, 256, 0, stream>>>(key,   Wk, bk, kbf, 1.0f);
    proj_kernel<<<gp, 256, 0, stream>>>(value, Wv, bv, vbf, 1.0f);

    (void)hipFuncSetAttribute((const void*)attn_mfma_kernel,
                              hipFuncAttributeMaxDynamicSharedMemorySize, SMEM_BYTES);
    attn_mfma_kernel<<<256, 512, SMEM_BYTES, stream>>>(qbf, kbf, vbf, kpm, out, attn);
}

// Round 3
// 66.792 us; speedup vs baseline: 7.6343x; 2.3014x over previous
//
#include <hip/hip_runtime.h>
#include <hip/hip_bf16.h>

#define TSEQ 256
#define NBATCH 2
#define NAG 8
#define NH 8
#define HD 64
#define EE 512
#define WHALF 16
#define WW 33
#define WN 264   // WW*NAG

typedef __attribute__((ext_vector_type(8))) short short8;
typedef __attribute__((ext_vector_type(4))) short short4v;
typedef __attribute__((ext_vector_type(4))) float f32x4;

// ---- attn dynamic LDS layout (bytes) ----
#define KS_OFF   0          // 384 rows x 128B (XOR-swizzled)      = 49152
#define VT_OFF   49152      // 64 rows x 768B  (XOR-swizzled)      = 49152
#define P_OFF    98304      // 32 rows x 1552B fp32 (+bf16 alias)  = 49664
#define QS_OFF   147968     // 32 rows x 128B  (XOR-swizzled)      = 4096
#define KM_OFF   152064     // 384B key-valid mask (+pad)
#define SMEM_BYTES 152576

static __device__ __forceinline__ unsigned short f2bf(float f) {
    unsigned int u = __float_as_uint(f);
    unsigned int r = (u + 0x7FFFu + ((u >> 16) & 1u)) >> 16;
    return (unsigned short)r;
}

// ---------------- fused QKV projection GEMM (bf16 MFMA) -----------------
// out[i,f] = (sum_e x[i,e]*W[f,e] + b[f]) * scale ; x:4096x512 fp32, W:512x512 fp32
// BM=128, BN=64, BK=64, 4 waves (2x2), 16x16x32 bf16 MFMA. z picks {q,k,v}.
__global__ __launch_bounds__(256)
void proj_mfma_kernel(const float* __restrict__ xq, const float* __restrict__ xk,
                      const float* __restrict__ xv,
                      const float* __restrict__ Wq, const float* __restrict__ Wk,
                      const float* __restrict__ Wv,
                      const float* __restrict__ bq, const float* __restrict__ bk,
                      const float* __restrict__ bv,
                      unsigned short* __restrict__ oq, unsigned short* __restrict__ ok,
                      unsigned short* __restrict__ ov)
{
    __shared__ char As[128 * 128];   // 128 rows x 64 bf16 (swizzled)
    __shared__ char Bs[64 * 128];    // 64 rows x 64 bf16 (swizzled)

    const float* x; const float* W; const float* bias;
    unsigned short* o; float scale;
    if (blockIdx.z == 0)      { x = xq; W = Wq; bias = bq; o = oq; scale = 0.125f; }
    else if (blockIdx.z == 1) { x = xk; W = Wk; bias = bk; o = ok; scale = 1.0f; }
    else                      { x = xv; W = Wv; bias = bv; o = ov; scale = 1.0f; }

    const int tid  = threadIdx.x;
    const int lane = tid & 63;
    const int wid  = tid >> 6;
    const int i0 = blockIdx.x * 128;
    const int f0 = blockIdx.y * 64;
    const int wr = wid >> 1, wc = wid & 1;

    f32x4 acc[4][2];
    #pragma unroll
    for (int m = 0; m < 4; ++m)
        #pragma unroll
        for (int n = 0; n < 2; ++n)
            acc[m][n] = (f32x4){0.f, 0.f, 0.f, 0.f};

    for (int k0 = 0; k0 < EE; k0 += 64) {
        // ---- stage A: 128 rows x 64 k, fp32 -> bf16, XOR swizzle ----
        #pragma unroll
        for (int it = 0; it < 8; ++it) {
            const int tt  = tid + it * 256;        // 0..2047
            const int row = tt >> 4, f4 = tt & 15;
            float4 v4 = *reinterpret_cast<const float4*>(x + (size_t)(i0 + row) * EE + k0 + f4 * 4);
            short4v s;
            s[0] = (short)f2bf(v4.x); s[1] = (short)f2bf(v4.y);
            s[2] = (short)f2bf(v4.z); s[3] = (short)f2bf(v4.w);
            *(short4v*)(As + row * 128 + ((f4 * 8) ^ ((row & 7) << 4))) = s;
        }
        // ---- stage B: 64 rows x 64 k ----
        #pragma unroll
        for (int it = 0; it < 4; ++it) {
            const int tt  = tid + it * 256;        // 0..1023
            const int row = tt >> 4, f4 = tt & 15;
            float4 v4 = *reinterpret_cast<const float4*>(W + (size_t)(f0 + row) * EE + k0 + f4 * 4);
            short4v s;
            s[0] = (short)f2bf(v4.x); s[1] = (short)f2bf(v4.y);
            s[2] = (short)f2bf(v4.z); s[3] = (short)f2bf(v4.w);
            *(short4v*)(Bs + row * 128 + ((f4 * 8) ^ ((row & 7) << 4))) = s;
        }
        __syncthreads();

        #pragma unroll
        for (int ks = 0; ks < 2; ++ks) {
            short8 a[4], b[2];
            #pragma unroll
            for (int m = 0; m < 4; ++m) {
                const int row = wr * 64 + m * 16 + (lane & 15);
                a[m] = *(short8*)(As + row * 128 +
                                  ((ks * 64 + (lane >> 4) * 16) ^ ((row & 7) << 4)));
            }
            #pragma unroll
            for (int n = 0; n < 2; ++n) {
                const int row = wc * 32 + n * 16 + (lane & 15);
                b[n] = *(short8*)(Bs + row * 128 +
                                  ((ks * 64 + (lane >> 4) * 16) ^ ((row & 7) << 4)));
            }
            #pragma unroll
            for (int m = 0; m < 4; ++m)
                #pragma unroll
                for (int n = 0; n < 2; ++n)
                    acc[m][n] = __builtin_amdgcn_mfma_f32_16x16x32_bf16(a[m], b[n], acc[m][n], 0, 0, 0);
        }
        __syncthreads();
    }

    // ---- epilogue: bias + scale, bf16 store ----
    #pragma unroll
    for (int n = 0; n < 2; ++n) {
        const int col = f0 + wc * 32 + n * 16 + (lane & 15);
        const float bb = bias[col];
        #pragma unroll
        for (int m = 0; m < 4; ++m) {
            #pragma unroll
            for (int rg = 0; rg < 4; ++rg) {
                const int row = i0 + wr * 64 + m * 16 + (lane >> 4) * 4 + rg;
                o[(size_t)row * EE + col] = f2bf((acc[m][n][rg] + bb) * scale);
            }
        }
    }
}

// ---------------- MFMA windowed attention -----------------
// grid: 256 blocks, bid = h*32 + (b*16 + tc); 512 threads.
__global__ __launch_bounds__(512, 1)
void attn_mfma_kernel(const unsigned short* __restrict__ qb,
                      const unsigned short* __restrict__ kb,
                      const unsigned short* __restrict__ vb,
                      const unsigned char* __restrict__ kpm,
                      float* __restrict__ out,
                      float* __restrict__ attn)
{
    extern __shared__ char smem[];
    const int bid = blockIdx.x;
    const int h   = bid >> 5;
    const int btc = bid & 31;
    const int b   = btc >> 4;
    const int tc  = btc & 15;
    const int t0  = tc * 16;
    const int j0  = t0 - WHALF;
    const int tid = threadIdx.x;
    const int lane = tid & 63;
    const int wid  = tid >> 6;

    // ---- stage K: 384 key-rows x 64 bf16, row stride 128B, XOR swizzle ----
    for (int tt = tid; tt < 3072; tt += 512) {
        const int row = tt >> 3, ch = tt & 7;
        const int jj = row >> 3, m = row & 7;
        const int j = j0 + jj;
        char* dst = smem + KS_OFF + row * 128 + ((ch * 16) ^ ((row & 7) << 4));
        if (j >= 0 && j < TSEQ) {
            *(short8*)dst = *(const short8*)(kb + (((size_t)(b * TSEQ + j) * NAG + m) * EE + h * HD + ch * 8));
        } else {
            short8 z = {0,0,0,0,0,0,0,0};
            *(short8*)dst = z;
        }
    }
    // ---- stage Vt (transposed): 64 d-rows x 384, row stride 768B, XOR swizzle ----
    for (int tt = tid; tt < 3072; tt += 512) {
        const int key = tt >> 3, dch = tt & 7;
        const int jj = key >> 3, m = key & 7;
        const int j = j0 + jj;
        unsigned short tv[8] = {0,0,0,0,0,0,0,0};
        if (j >= 0 && j < TSEQ) {
            short8 val = *(const short8*)(vb + (((size_t)(b * TSEQ + j) * NAG + m) * EE + h * HD + dch * 8));
            #pragma unroll
            for (int i = 0; i < 8; ++i) tv[i] = (unsigned short)val[i];
        }
        #pragma unroll
        for (int i = 0; i < 8; ++i) {
            const int d = dch * 8 + i;
            *(unsigned short*)(smem + VT_OFF + d * 768 + ((key * 2) ^ ((d & 7) << 4))) = tv[i];
        }
    }
    // ---- key-valid mask ----
    if (tid < 384) {
        const int jj = tid >> 3, m = tid & 7;
        const int j = j0 + jj;
        smem[KM_OFF + tid] = (j >= 0 && j < TSEQ && kpm[(b * TSEQ + j) * NAG + m] == 0) ? 1 : 0;
    }
    __syncthreads();

    for (int sub = 0; sub < 4; ++sub) {
        const int ts0 = t0 + sub * 4;    // 4 t-values, 32 query rows

        // ---- stage Qs: 32 rows x 64 bf16 ----
        if (tid < 256) {
            const int rr = tid >> 3, ch = tid & 7;
            const int t = ts0 + (rr >> 3), n = rr & 7;
            char* dst = smem + QS_OFF + rr * 128 + ((ch * 16) ^ ((rr & 7) << 4));
            *(short8*)dst = *(const short8*)(qb + (((size_t)(b * TSEQ + t) * NAG + n) * EE + h * HD + ch * 8));
        }
        __syncthreads();

        // ---- QK^T: D[32 x 384]; wave: rfrag = wid&1, colfrags cf = (wid>>1)+4*i ----
        {
            f32x4 acc[6];
            #pragma unroll
            for (int i = 0; i < 6; ++i) acc[i] = (f32x4){0.f, 0.f, 0.f, 0.f};
            const int arow = (wid & 1) * 16 + (lane & 15);
            #pragma unroll
            for (int ks = 0; ks < 2; ++ks) {
                short8 afr = *(short8*)(smem + QS_OFF + arow * 128 +
                                        ((ks * 64 + (lane >> 4) * 16) ^ ((arow & 7) << 4)));
                #pragma unroll
                for (int i = 0; i < 6; ++i) {
                    const int cf = (wid >> 1) + 4 * i;
                    const int krow = cf * 16 + (lane & 15);
                    short8 bfr = *(short8*)(smem + KS_OFF + krow * 128 +
                                            ((ks * 64 + (lane >> 4) * 16) ^ ((krow & 7) << 4)));
                    acc[i] = __builtin_amdgcn_mfma_f32_16x16x32_bf16(afr, bfr, acc[i], 0, 0, 0);
                }
            }
            #pragma unroll
            for (int i = 0; i < 6; ++i) {
                const int cf = (wid >> 1) + 4 * i;
                const int col = cf * 16 + (lane & 15);
                const int r0 = (wid & 1) * 16 + (lane >> 4) * 4;
                #pragma unroll
                for (int rg = 0; rg < 4; ++rg)
                    ((float*)(smem + P_OFF + (size_t)(r0 + rg) * 1552))[col] = acc[i][rg];
            }
        }
        __syncthreads();

        // ---- softmax + attn store + bf16 repack (row rr owned by 16 lanes of one wave) ----
        {
            const int rr = tid >> 4, s16 = tid & 15;
            const int dtile = sub * 4 + (rr >> 3);
            const int win0 = dtile * 8;
            const int t = t0 + dtile, n = rr & 7;
            float* prow = (float*)(smem + P_OFF + (size_t)rr * 1552);
            const unsigned char* km = (const unsigned char*)(smem + KM_OFF);

            float vals[17];
            float mx = -INFINITY;
            #pragma unroll
            for (int k2 = 0; k2 < 17; ++k2) {
                const int cc = s16 + 16 * k2;
                float xv = -INFINITY;
                if (cc < WN) {
                    const int c = win0 + cc;
                    if (km[c]) xv = prow[c];
                }
                vals[k2] = xv;
                mx = fmaxf(mx, xv);
            }
            mx = fmaxf(mx, __shfl_xor(mx, 1));
            mx = fmaxf(mx, __shfl_xor(mx, 2));
            mx = fmaxf(mx, __shfl_xor(mx, 4));
            mx = fmaxf(mx, __shfl_xor(mx, 8));
            float sum = 0.f;
            #pragma unroll
            for (int k2 = 0; k2 < 17; ++k2) {
                const float p = (vals[k2] == -INFINITY) ? 0.f : __expf(vals[k2] - mx);
                vals[k2] = p;
                sum += p;
            }
            sum += __shfl_xor(sum, 1);
            sum += __shfl_xor(sum, 2);
            sum += __shfl_xor(sum, 4);
            sum += __shfl_xor(sum, 8);
            const float inv = 1.f / sum;
            #pragma unroll
            for (int k2 = 0; k2 < 17; ++k2) {
                const int cc = s16 + 16 * k2;
                if (cc < WN) prow[win0 + cc] = vals[k2] * inv;
            }

            // conversion + global attn write: read fp32 (all window cols), stash, then bf16 write
            const int c0 = s16;
            float pr[24];
            float* ap = attn + ((((size_t)(b * TSEQ + t) * NAG + n) * WN) * NH + h);
            #pragma unroll
            for (int k2 = 0; k2 < 24; ++k2) {
                const int c = c0 + 16 * k2;
                const bool in = (c >= win0) && (c < win0 + WN);
                float p = 0.f;
                if (in) p = prow[c];
                pr[k2] = p;
                if (in) ap[(size_t)(c - win0) * NH] = p;
            }
            // ensure all LDS reads above have completed before aliasing bf16 writes
            __builtin_amdgcn_sched_barrier(0);
            asm volatile("s_waitcnt lgkmcnt(0)" ::: "memory");
            __builtin_amdgcn_sched_barrier(0);
            #pragma unroll
            for (int k2 = 0; k2 < 24; ++k2) {
                const int c = c0 + 16 * k2;
                const int ib = (2 * c) ^ ((rr & 7) << 4);
                *(unsigned short*)(smem + P_OFF + (size_t)rr * 1552 + ib) = f2bf(pr[k2]);
            }
        }
        __syncthreads();

        // ---- PV: D[32 x 64]; wave: rfrag = wid&1, dfrag = wid>>1 ----
        {
            f32x4 acc = (f32x4){0.f, 0.f, 0.f, 0.f};
            const int rfrag = wid & 1, dfrag = wid >> 1;
            const int arow = rfrag * 16 + (lane & 15);
            const int drow = dfrag * 16 + (lane & 15);
            #pragma unroll
            for (int ms = 0; ms < 12; ++ms) {
                short8 afr = *(short8*)(smem + P_OFF + (size_t)arow * 1552 +
                                        ((ms * 64 + (lane >> 4) * 16) ^ ((arow & 7) << 4)));
                short8 bfr = *(short8*)(smem + VT_OFF + drow * 768 +
                                        ((ms * 64 + (lane >> 4) * 16) ^ ((drow & 7) << 4)));
                acc = __builtin_amdgcn_mfma_f32_16x16x32_bf16(afr, bfr, acc, 0, 0, 0);
            }
            const int r0 = rfrag * 16 + (lane >> 4) * 4;
            const int d = dfrag * 16 + (lane & 15);
            #pragma unroll
            for (int rg = 0; rg < 4; ++rg) {
                const int rr = r0 + rg;
                const int t = ts0 + (rr >> 3), n = rr & 7;
                out[((size_t)(b * TSEQ + t) * NAG + n) * EE + h * HD + d] = acc[rg];
            }
        }
        __syncthreads();   // protect P32/Qs overwrite next sub
    }
}

extern "C" void kernel_launch(void* const* d_in, const int* in_sizes, int n_in,
                              void* d_out, int out_size, void* d_ws, size_t ws_size,
                              hipStream_t stream) {
    const float* query = (const float*)d_in[0];
    const float* key   = (const float*)d_in[1];
    const float* value = (const float*)d_in[2];
    const unsigned char* kpm = (const unsigned char*)d_in[3];
    const float* Wq = (const float*)d_in[4];
    const float* bq = (const float*)d_in[5];
    const float* Wk = (const float*)d_in[6];
    const float* bk = (const float*)d_in[7];
    const float* Wv = (const float*)d_in[8];
    const float* bv = (const float*)d_in[9];

    float* out  = (float*)d_out;
    float* attn = out + (size_t)NBATCH * TSEQ * NAG * EE;

    unsigned short* qbf = (unsigned short*)d_ws;               // 3 x 4 MB bf16
    unsigned short* kbf = qbf + (size_t)4096 * EE;
    unsigned short* vbf = kbf + (size_t)4096 * EE;

    dim3 gp(32, 8, 3);   // M-tiles x N-tiles x {q,k,v}
    proj_mfma_kernel<<<gp, 256, 0, stream>>>(query, key, value,
                                             Wq, Wk, Wv,
                                             bq, bk, bv,
                                             qbf, kbf, vbf);

    (void)hipFuncSetAttribute((const void*)attn_mfma_kernel,
                              hipFuncAttributeMaxDynamicSharedMemorySize, SMEM_BYTES);
    attn_mfma_kernel<<<256, 512, SMEM_BYTES, stream>>>(qbf, kbf, vbf, kpm, out, attn);
}